// Round 4
// baseline (74660.577 us; speedup 1.0000x reference)
//
#include <hip/hip_runtime.h>
#include <math.h>

#define TT 8192
#define DD 1024
#define NWG 256   // 128 WGs layer-1, 128 WGs layer-2
#define TPB 512   // 8 waves
#define GCAP (1 << 18)

// ---- coherent (cross-XCD) ops: sc0 sc1 bypass L1/L2, serviced at LLC ----
__device__ __forceinline__ void cstore_nd(float* p, float v) {
  asm volatile("global_store_dword %0, %1, off sc0 sc1" :: "v"(p), "v"(v) : "memory");
}
__device__ __forceinline__ void vdrain() { asm volatile("s_waitcnt vmcnt(0)" ::: "memory"); }
__device__ __forceinline__ float4 cload4(const float* p) {
  float4 r;
  asm volatile("global_load_dwordx4 %0, %1, off sc0 sc1\n\ts_waitcnt vmcnt(0)"
               : "=&v"(r) : "v"(p) : "memory");
  return r;
}
__device__ __forceinline__ unsigned cload_u32(const unsigned* p) {
  unsigned r;
  asm volatile("global_load_dword %0, %1, off sc0 sc1\n\ts_waitcnt vmcnt(0)"
               : "=&v"(r) : "v"(p) : "memory");
  return r;
}

// Counter lines: kind(0=h,1=r) x layer x slot(8) x subline(4), 128B padded.
// Monotone epoch-encoded: line value after tick t's publish = 32*((t>>3)+1).
__device__ __forceinline__ unsigned* cline(unsigned* cnt, int kind, int layer,
                                           int slot, int q) {
  return cnt + (((((kind << 1) + layer) * 8 + slot) * 4 + q) << 5);
}

// arena: h1s[8*DD] | h2s[8*DD] | r1s[8*2DD] | r2s[8*2DD] = 48*DD floats
__global__ void init_arena(float* __restrict__ arena, unsigned* __restrict__ cnt) {
  const int idx = blockIdx.x * 256 + threadIdx.x;
  if (idx < 48 * DD) arena[idx] = 0.f;
  const int c = idx - 48 * DD;
  if (c >= 0 && c < 4096) cnt[c] = 0u;
}

// Persistent dataflow 2-layer CRSD, flag-gated bulk exchange.
// WGs 0..127: layer 1; WGs 128..255: layer 2 (consumes h1_t same tick).
// Wave wv of wg7 owns pre-row row=wg7*8+wv and U-rows (k=0,row),(k=1,row).
__global__ __launch_bounds__(TPB, 2)
void crsd_seq(const float* __restrict__ pwx, const float* __restrict__ Wx,
              const float* __restrict__ Wh, const float* __restrict__ Wr,
              const float* __restrict__ Uw, const float* __restrict__ bias,
              float* __restrict__ out, float* __restrict__ arena,
              unsigned* __restrict__ cnt) {
  const int wg = blockIdx.x, tid = threadIdx.x;
  const int wv = tid >> 6, ln = tid & 63;
  const int layer = wg >> 7, wg7 = wg & 127;
  const int row = wg7 * 8 + wv;
  const int myq = wg7 >> 5;           // which of 4 counter sublines this WG bumps
  const size_t MS = (size_t)DD * DD;

  float* h1s = arena;
  float* h2s = arena + 8 * DD;
  float* r1s = arena + 16 * DD;
  float* r2s = arena + 32 * DD;
  float* hS = layer ? h2s : h1s;
  float* rS = layer ? r2s : r1s;

  __shared__ __align__(16) float sh_x[DD];
  __shared__ __align__(16) float sh_h[DD];
  __shared__ __align__(16) float sh_r[2 * DD];

  const float* Whp = Wh + (size_t)layer * MS;
  const float* Wrp = Wr + (size_t)layer * 2 * MS;
  const float* Up  = Uw + (size_t)layer * 2 * MS;

  // ---- one-time weight load into registers ----
  float wh[16], wr0[16], wr1[16], wx[16], uw[2][16];
#pragma unroll
  for (int c = 0; c < 4; ++c) {
    const int j = 4 * ln + 256 * c;
    float4 a = *(const float4*)&Whp[(size_t)row * DD + j];
    wh[4*c+0]=a.x; wh[4*c+1]=a.y; wh[4*c+2]=a.z; wh[4*c+3]=a.w;
    float4 b0 = *(const float4*)&Wrp[(size_t)row * DD + j];
    wr0[4*c+0]=b0.x; wr0[4*c+1]=b0.y; wr0[4*c+2]=b0.z; wr0[4*c+3]=b0.w;
    float4 b1 = *(const float4*)&Wrp[MS + (size_t)row * DD + j];
    wr1[4*c+0]=b1.x; wr1[4*c+1]=b1.y; wr1[4*c+2]=b1.z; wr1[4*c+3]=b1.w;
    if (layer) {
      float4 xw = *(const float4*)&Wx[MS + (size_t)row * DD + j];
      wx[4*c+0]=xw.x; wx[4*c+1]=xw.y; wx[4*c+2]=xw.z; wx[4*c+3]=xw.w;
    } else {
      wx[4*c+0]=0.f; wx[4*c+1]=0.f; wx[4*c+2]=0.f; wx[4*c+3]=0.f;
    }
#pragma unroll
    for (int s2 = 0; s2 < 2; ++s2) {
      float4 u4 = *(const float4*)&Up[(size_t)s2 * MS + (size_t)row * DD + j];
      uw[s2][4*c+0]=u4.x; uw[s2][4*c+1]=u4.y; uw[s2][4*c+2]=u4.z; uw[s2][4*c+3]=u4.w;
    }
  }
  const float bb = layer ? bias[DD + row] : 0.f;
  float rown[2] = {0.f, 0.f};
  // h_{-1} = 0 (sh_h is kept live across ticks; phase B reloads it each tick)
  sh_h[tid] = 0.f;
  sh_h[tid + 512] = 0.f;

  for (int t = 0; t < TT; ++t) {
    const int cu = t & 7, pv = (t - 1) & 7;

    // ---- phase A gate: wave 0 polls ready-counters, everyone else waits ----
    if (wv == 0) {
      const unsigned* ap = nullptr;
      unsigned tgt = 0;
      bool need = false;
      if (ln < 4) {                       // r_{t-1} ready (own layer)
        if (t > 0) {
          need = true;
          ap = cline(cnt, 1, layer, pv, ln);
          tgt = 32u * ((unsigned)((t - 1) >> 3) + 1u);
        }
      } else if (ln < 8) {
        if (layer) {                      // h1_t ready (layer-2 input)
          need = true;
          ap = cline(cnt, 0, 0, cu, ln - 4);
          tgt = 32u * ((unsigned)(t >> 3) + 1u);
        } else if (t >= 8) {              // backpressure: L2 consumed h1 of t-8
          need = true;
          ap = cline(cnt, 1, 1, cu, ln - 4);
          tgt = 32u * (unsigned)(t >> 3);
        }
      }
      if (__any((int)need)) {
        int g = 0;
        for (;;) {
          bool ok = true;
          if (need) ok = (cload_u32(ap) >= tgt);
          if (__all((int)ok)) break;
          if (++g > GCAP) break;
          __builtin_amdgcn_s_sleep(2);
        }
      }
    }
    __syncthreads();

    // ---- bulk stage (exactly once per value) ----
    *(float4*)&sh_r[4 * tid] = cload4(rS + pv * 2 * DD + 4 * tid);
    if (layer && tid < 256)
      *(float4*)&sh_x[4 * tid] = cload4(h1s + cu * DD + 4 * tid);
    const float pw = (!layer && ln == 0) ? pwx[(size_t)t * DD + row] : 0.f;
    __syncthreads();

    // ---- compute pre-row, publish h_t ----
    float acc = 0.f;
#pragma unroll
    for (int c = 0; c < 4; ++c) {
      const int j = 4 * ln + 256 * c;
      const float4 hv = *(const float4*)&sh_h[j];
      const float4 r0 = *(const float4*)&sh_r[j];
      const float4 r1v = *(const float4*)&sh_r[DD + j];
      acc += wh[4*c+0]*hv.x + wh[4*c+1]*hv.y + wh[4*c+2]*hv.z + wh[4*c+3]*hv.w
           + wr0[4*c+0]*r0.x + wr0[4*c+1]*r0.y + wr0[4*c+2]*r0.z + wr0[4*c+3]*r0.w
           + wr1[4*c+0]*r1v.x + wr1[4*c+1]*r1v.y + wr1[4*c+2]*r1v.z + wr1[4*c+3]*r1v.w;
      if (layer) {
        const float4 xv = *(const float4*)&sh_x[j];
        acc += wx[4*c+0]*xv.x + wx[4*c+1]*xv.y + wx[4*c+2]*xv.z + wx[4*c+3]*xv.w;
      }
    }
#pragma unroll
    for (int off = 32; off; off >>= 1) acc += __shfl_xor(acc, off, 64);
    if (ln == 0) {
      const float hn = tanhf(acc + (layer ? bb : pw));
      cstore_nd(hS + cu * DD + row, hn);
      if (layer) out[(size_t)t * DD + row] = hn;
    }
    vdrain();          // wave-level: this wave's h store is at the LLC
    __syncthreads();   // all 8 rows of this WG are at the LLC
    if (tid == 0)
      __hip_atomic_fetch_add(cline(cnt, 0, layer, cu, myq), 1u,
                             __ATOMIC_RELAXED, __HIP_MEMORY_SCOPE_AGENT);

    // ---- phase B gate: h_t fully ready? ----
    if (wv == 0 && ln < 4) {
      const unsigned* ap = cline(cnt, 0, layer, cu, ln);
      const unsigned tgt = 32u * ((unsigned)(t >> 3) + 1u);
      int g = 0;
      for (;;) {
        bool ok = (ln >= 4) || (cload_u32(ap) >= tgt);
        if (__all((int)ok)) break;
        if (++g > GCAP) break;
        __builtin_amdgcn_s_sleep(2);
      }
    }
    __syncthreads();
    if (tid < 256)
      *(float4*)&sh_h[4 * tid] = cload4(hS + cu * DD + 4 * tid);
    __syncthreads();

    // ---- r update from full h_t, publish r_t ----
#pragma unroll
    for (int s2 = 0; s2 < 2; ++s2) {
      float a = 0.f;
#pragma unroll
      for (int c = 0; c < 4; ++c) {
        const int j = 4 * ln + 256 * c;
        const float4 hv = *(const float4*)&sh_h[j];
        a += uw[s2][4*c+0]*hv.x + uw[s2][4*c+1]*hv.y
           + uw[s2][4*c+2]*hv.z + uw[s2][4*c+3]*hv.w;
      }
#pragma unroll
      for (int off = 32; off; off >>= 1) a += __shfl_xor(a, off, 64);
      if (ln == 0) {
        rown[s2] = 0.9f * rown[s2] + 0.1f * tanhf(a);
        cstore_nd(rS + cu * 2 * DD + s2 * DD + row, rown[s2]);
      }
    }
    vdrain();
    __syncthreads();
    if (tid == 0)
      __hip_atomic_fetch_add(cline(cnt, 1, layer, cu, myq), 1u,
                             __ATOMIC_RELAXED, __HIP_MEMORY_SCOPE_AGENT);
  }
}

// C[M][1024] = A[M][1024] @ W^T + bias   (W row-major [1024][1024])
__global__ __launch_bounds__(256)
void gemm_bias(const float* __restrict__ A, const float* __restrict__ W,
               const float* __restrict__ bias, float* __restrict__ C) {
  __shared__ float As[32][65];
  __shared__ float Ws[32][65];
  const int tid = threadIdx.x;
  const int bm = blockIdx.x * 64;
  const int bn = blockIdx.y * 64;
  const int ty = tid >> 4, tx = tid & 15;
  float acc[4][4] = {};
  for (int k0 = 0; k0 < DD; k0 += 32) {
#pragma unroll
    for (int p = 0; p < 2; ++p) {
      const int idx = tid + p * 256;
      const int r = idx >> 3;
      const int cf = idx & 7;
      float4 av = *(const float4*)&A[(size_t)(bm + r) * DD + k0 + cf * 4];
      As[cf*4+0][r] = av.x; As[cf*4+1][r] = av.y; As[cf*4+2][r] = av.z; As[cf*4+3][r] = av.w;
      float4 wv = *(const float4*)&W[(size_t)(bn + r) * DD + k0 + cf * 4];
      Ws[cf*4+0][r] = wv.x; Ws[cf*4+1][r] = wv.y; Ws[cf*4+2][r] = wv.z; Ws[cf*4+3][r] = wv.w;
    }
    __syncthreads();
#pragma unroll
    for (int kk = 0; kk < 32; ++kk) {
      float a[4], w[4];
#pragma unroll
      for (int e = 0; e < 4; ++e) { a[e] = As[kk][ty * 4 + e]; w[e] = Ws[kk][tx * 4 + e]; }
#pragma unroll
      for (int i = 0; i < 4; ++i)
#pragma unroll
        for (int j = 0; j < 4; ++j) acc[i][j] += a[i] * w[j];
    }
    __syncthreads();
  }
#pragma unroll
  for (int i = 0; i < 4; ++i) {
    const int m = bm + ty * 4 + i;
#pragma unroll
    for (int j = 0; j < 4; ++j) {
      const int n = bn + tx * 4 + j;
      C[(size_t)m * DD + n] = acc[i][j] + bias[n];
    }
  }
}

extern "C" void kernel_launch(void* const* d_in, const int* in_sizes, int n_in,
                              void* d_out, int out_size, void* d_ws, size_t ws_size,
                              hipStream_t stream) {
  const float* x  = (const float*)d_in[0];
  const float* Wx = (const float*)d_in[1];
  const float* Wh = (const float*)d_in[2];
  const float* Wr = (const float*)d_in[3];
  const float* U  = (const float*)d_in[4];
  const float* b  = (const float*)d_in[5];
  float* out = (float*)d_out;

  float* pwx = (float*)d_ws;                 // [T][D] fp32 = 32 MB
  float* arena = pwx + (size_t)TT * DD;      // 48*DD floats
  unsigned* cnt = (unsigned*)(arena + 48 * DD);  // 4096 u32 (16 KB, padded lines)

  hipLaunchKernelGGL(init_arena, dim3((48 * DD + 4096 + 255) / 256), dim3(256),
                     0, stream, arena, cnt);
  hipLaunchKernelGGL(gemm_bias, dim3(TT / 64, DD / 64), dim3(256), 0, stream,
                     x, Wx, b, pwx);  // layer-1 pwx = x @ Wx1^T + b1

  const float* pwxc = pwx;
  float* arenap = arena;
  unsigned* cntp = cnt;
  void* args[] = { (void*)&pwxc, (void*)&Wx, (void*)&Wh, (void*)&Wr,
                   (void*)&U, (void*)&b, (void*)&out, (void*)&arenap, (void*)&cntp };
  hipLaunchCooperativeKernel((const void*)crsd_seq, dim3(NWG), dim3(TPB),
                             args, 0, stream);
}

// Round 5
// 60952.600 us; speedup vs baseline: 1.2249x; 1.2249x over previous
//
#include <hip/hip_runtime.h>
#include <math.h>

#define TT 8192
#define DD 1024
#define LWG 64    // WGs per layer
#define NWG 128   // total
#define TPB 512   // 8 waves; each wave owns 2 pre-rows
#define GCAP (1 << 17)

typedef __attribute__((ext_vector_type(2))) float f32x2;

// ---- coherent (cross-XCD) ops: sc0 sc1 bypass L1/L2, serviced at LLC ----
__device__ __forceinline__ void vdrain() { asm volatile("s_waitcnt vmcnt(0)" ::: "memory"); }
__device__ __forceinline__ void cstore2_nd(float* p, f32x2 v) {
  asm volatile("global_store_dwordx2 %0, %1, off sc0 sc1" :: "v"(p), "v"(v) : "memory");
}
__device__ __forceinline__ void cstoreu_nd(unsigned* p, unsigned v) {
  asm volatile("global_store_dword %0, %1, off sc0 sc1" :: "v"(p), "v"(v) : "memory");
}
__device__ __forceinline__ float4 cload4(const float* p) {
  float4 r;
  asm volatile("global_load_dwordx4 %0, %1, off sc0 sc1\n\ts_waitcnt vmcnt(0)"
               : "=&v"(r) : "v"(p) : "memory");
  return r;
}
__device__ __forceinline__ void cload4x2(const float* p0, const float* p1,
                                         float4& a, float4& b) {
  asm volatile("global_load_dwordx4 %0, %2, off sc0 sc1\n\t"
               "global_load_dwordx4 %1, %3, off sc0 sc1\n\t"
               "s_waitcnt vmcnt(0)"
               : "=&v"(a), "=&v"(b) : "v"(p0), "v"(p1) : "memory");
}
__device__ __forceinline__ unsigned cload_u32(const unsigned* p) {
  unsigned r;
  asm volatile("global_load_dword %0, %1, off sc0 sc1\n\ts_waitcnt vmcnt(0)"
               : "=&v"(r) : "v"(p) : "memory");
  return r;
}

// Tag arrays: [kind(0=h,1=r)][layer][slot(8)][LWG] u32, dense, no atomics.
// Producer g stores (t>>3)+1 into its own word after its data drains.
__device__ __forceinline__ unsigned* tagp(unsigned* tg, int kind, int layer,
                                          int slot, int idx) {
  return tg + (((kind * 2 + layer) * 8 + slot) * LWG) + idx;
}

// All-lane poll of a 64-word tag array; exits when all >= tgt. Capped.
__device__ __forceinline__ void pollgate(const unsigned* base, int ln, unsigned tgt) {
  const unsigned* p = base + ln;
  int g = 0;
  for (;;) {
    const unsigned v = cload_u32(p);
    if (__all((int)(v >= tgt))) break;
    if (++g > GCAP) break;
  }
}

// arena: h1s[8*DD] | h2s[8*DD] | r1s[8*2DD] | r2s[8*2DD] = 48*DD floats; tags after.
__global__ void init_arena(float* __restrict__ arena, unsigned* __restrict__ tg) {
  const int idx = blockIdx.x * 256 + threadIdx.x;
  if (idx < 48 * DD) arena[idx] = 0.f;
  const int c = idx - 48 * DD;
  if (c >= 0 && c < 2 * 2 * 8 * LWG) tg[c] = 0u;
}

// Persistent dataflow 2-layer CRSD. WGs 0..63: layer 1; 64..127: layer 2.
// Wave wv of g owns pre-rows rb=g*16+2*wv, rb+1 and U-rows (k,rb),(k,rb+1).
__global__ __launch_bounds__(TPB, 1)
void crsd_seq(const float* __restrict__ pwx, const float* __restrict__ Wx,
              const float* __restrict__ Wh, const float* __restrict__ Wr,
              const float* __restrict__ Uw, const float* __restrict__ bias,
              float* __restrict__ out, float* __restrict__ arena,
              unsigned* __restrict__ tg) {
  const int wg = blockIdx.x, tid = threadIdx.x;
  const int wv = tid >> 6, ln = tid & 63;
  const int layer = wg >> 6, g = wg & 63;
  const int rb = g * 16 + 2 * wv;
  const size_t MS = (size_t)DD * DD;

  float* h1s = arena;
  float* h2s = arena + 8 * DD;
  float* r1s = arena + 16 * DD;
  float* r2s = arena + 32 * DD;
  float* hS = layer ? h2s : h1s;
  float* rS = layer ? r2s : r1s;

  __shared__ __align__(16) float sh_x[DD];
  __shared__ __align__(16) float sh_h[DD];
  __shared__ __align__(16) float sh_r[2 * DD];

  const float* Whp = Wh + (size_t)layer * MS;
  const float* Wrp = Wr + (size_t)layer * 2 * MS;
  const float* Up  = Uw + (size_t)layer * 2 * MS;

  // ---- one-time weight load into registers (2 rows per wave) ----
  float wh[2][16], wr[2][2][16], wx[2][16], uw[2][2][16];
#pragma unroll
  for (int ri = 0; ri < 2; ++ri) {
    const int row = rb + ri;
#pragma unroll
    for (int c = 0; c < 4; ++c) {
      const int j = 4 * ln + 256 * c;
      float4 a = *(const float4*)&Whp[(size_t)row * DD + j];
      wh[ri][4*c+0]=a.x; wh[ri][4*c+1]=a.y; wh[ri][4*c+2]=a.z; wh[ri][4*c+3]=a.w;
      float4 b0 = *(const float4*)&Wrp[(size_t)row * DD + j];
      wr[ri][0][4*c+0]=b0.x; wr[ri][0][4*c+1]=b0.y; wr[ri][0][4*c+2]=b0.z; wr[ri][0][4*c+3]=b0.w;
      float4 b1 = *(const float4*)&Wrp[MS + (size_t)row * DD + j];
      wr[ri][1][4*c+0]=b1.x; wr[ri][1][4*c+1]=b1.y; wr[ri][1][4*c+2]=b1.z; wr[ri][1][4*c+3]=b1.w;
      if (layer) {
        float4 xw = *(const float4*)&Wx[MS + (size_t)row * DD + j];
        wx[ri][4*c+0]=xw.x; wx[ri][4*c+1]=xw.y; wx[ri][4*c+2]=xw.z; wx[ri][4*c+3]=xw.w;
      } else {
        wx[ri][4*c+0]=0.f; wx[ri][4*c+1]=0.f; wx[ri][4*c+2]=0.f; wx[ri][4*c+3]=0.f;
      }
      float4 u0 = *(const float4*)&Up[(size_t)row * DD + j];
      uw[0][ri][4*c+0]=u0.x; uw[0][ri][4*c+1]=u0.y; uw[0][ri][4*c+2]=u0.z; uw[0][ri][4*c+3]=u0.w;
      float4 u1 = *(const float4*)&Up[MS + (size_t)row * DD + j];
      uw[1][ri][4*c+0]=u1.x; uw[1][ri][4*c+1]=u1.y; uw[1][ri][4*c+2]=u1.z; uw[1][ri][4*c+3]=u1.w;
    }
  }
  float bb0 = 0.f, bb1 = 0.f;
  if (layer) { bb0 = bias[DD + rb]; bb1 = bias[DD + rb + 1]; }
  float rown[2][2] = {{0.f, 0.f}, {0.f, 0.f}};  // owned r values (lane 0)
  // h_{-1} = 0; sh_h stays live across ticks (phase B refreshes it)
  sh_h[tid] = 0.f;
  sh_h[tid + 512] = 0.f;

  for (int t = 0; t < TT; ++t) {
    const int cu = t & 7, pv = (t - 1) & 7;
    const unsigned ep = (unsigned)((t >> 3) + 1);

    // ---- phase A gates (waves 0 and 1 poll concurrently) ----
    if (wv == 0) {
      if (t > 0) pollgate(tagp(tg, 1, layer, pv, 0), ln, (unsigned)(((t - 1) >> 3) + 1));
    } else if (wv == 1) {
      if (layer) pollgate(tagp(tg, 0, 0, cu, 0), ln, ep);            // h1_t ready
      else if (t >= 8) pollgate(tagp(tg, 1, 1, cu, 0), ln, (unsigned)(t >> 3));  // bp
    }
    __syncthreads();

    // ---- bulk stage (exactly once per value) ----
    if (layer && tid < 256) {
      float4 rv, xv;
      cload4x2(rS + pv * 2 * DD + 4 * tid, h1s + cu * DD + 4 * tid, rv, xv);
      *(float4*)&sh_r[4 * tid] = rv;
      *(float4*)&sh_x[4 * tid] = xv;
    } else {
      *(float4*)&sh_r[4 * tid] = cload4(rS + pv * 2 * DD + 4 * tid);
    }
    float pw0 = 0.f, pw1 = 0.f;
    if (!layer && ln == 0) {
      const f32x2 p2 = *(const f32x2*)&pwx[(size_t)t * DD + rb];
      pw0 = p2.x; pw1 = p2.y;
    }
    __syncthreads();

    // ---- compute 2 pre-rows, publish h_t ----
    float acc0 = 0.f, acc1 = 0.f;
#pragma unroll
    for (int c = 0; c < 4; ++c) {
      const int j = 4 * ln + 256 * c;
      const float4 hv = *(const float4*)&sh_h[j];
      const float4 r0 = *(const float4*)&sh_r[j];
      const float4 r1v = *(const float4*)&sh_r[DD + j];
      acc0 += wh[0][4*c+0]*hv.x + wh[0][4*c+1]*hv.y + wh[0][4*c+2]*hv.z + wh[0][4*c+3]*hv.w
            + wr[0][0][4*c+0]*r0.x + wr[0][0][4*c+1]*r0.y + wr[0][0][4*c+2]*r0.z + wr[0][0][4*c+3]*r0.w
            + wr[0][1][4*c+0]*r1v.x + wr[0][1][4*c+1]*r1v.y + wr[0][1][4*c+2]*r1v.z + wr[0][1][4*c+3]*r1v.w;
      acc1 += wh[1][4*c+0]*hv.x + wh[1][4*c+1]*hv.y + wh[1][4*c+2]*hv.z + wh[1][4*c+3]*hv.w
            + wr[1][0][4*c+0]*r0.x + wr[1][0][4*c+1]*r0.y + wr[1][0][4*c+2]*r0.z + wr[1][0][4*c+3]*r0.w
            + wr[1][1][4*c+0]*r1v.x + wr[1][1][4*c+1]*r1v.y + wr[1][1][4*c+2]*r1v.z + wr[1][1][4*c+3]*r1v.w;
      if (layer) {
        const float4 xv = *(const float4*)&sh_x[j];
        acc0 += wx[0][4*c+0]*xv.x + wx[0][4*c+1]*xv.y + wx[0][4*c+2]*xv.z + wx[0][4*c+3]*xv.w;
        acc1 += wx[1][4*c+0]*xv.x + wx[1][4*c+1]*xv.y + wx[1][4*c+2]*xv.z + wx[1][4*c+3]*xv.w;
      }
    }
#pragma unroll
    for (int off = 32; off; off >>= 1) {
      acc0 += __shfl_xor(acc0, off, 64);
      acc1 += __shfl_xor(acc1, off, 64);
    }
    if (ln == 0) {
      f32x2 h2;
      h2.x = tanhf(acc0 + (layer ? bb0 : pw0));
      h2.y = tanhf(acc1 + (layer ? bb1 : pw1));
      cstore2_nd(hS + cu * DD + rb, h2);
      if (layer) *(f32x2*)&out[(size_t)t * DD + rb] = h2;
    }
    vdrain();          // this wave's h rows are at the LLC
    __syncthreads();   // all 16 rows of this WG are at the LLC
    if (tid == 0) cstoreu_nd(tagp(tg, 0, layer, cu, 0) + g, ep);

    // ---- phase B gate: h_t fully ready? ----
    if (wv == 0) pollgate(tagp(tg, 0, layer, cu, 0), ln, ep);
    __syncthreads();
    if (tid < 256)
      *(float4*)&sh_h[4 * tid] = cload4(hS + cu * DD + 4 * tid);
    __syncthreads();

    // ---- r update from full h_t (4 owned U-rows), publish r_t ----
    float ua[2][2];
#pragma unroll
    for (int k = 0; k < 2; ++k)
#pragma unroll
      for (int ri = 0; ri < 2; ++ri) {
        float a = 0.f;
#pragma unroll
        for (int c = 0; c < 4; ++c) {
          const int j = 4 * ln + 256 * c;
          const float4 hv = *(const float4*)&sh_h[j];
          a += uw[k][ri][4*c+0]*hv.x + uw[k][ri][4*c+1]*hv.y
             + uw[k][ri][4*c+2]*hv.z + uw[k][ri][4*c+3]*hv.w;
        }
#pragma unroll
        for (int off = 32; off; off >>= 1) a += __shfl_xor(a, off, 64);
        ua[k][ri] = a;
      }
    if (ln == 0) {
#pragma unroll
      for (int k = 0; k < 2; ++k) {
        rown[k][0] = 0.9f * rown[k][0] + 0.1f * tanhf(ua[k][0]);
        rown[k][1] = 0.9f * rown[k][1] + 0.1f * tanhf(ua[k][1]);
        f32x2 rv; rv.x = rown[k][0]; rv.y = rown[k][1];
        cstore2_nd(rS + cu * 2 * DD + k * DD + rb, rv);
      }
    }
    vdrain();
    __syncthreads();
    if (tid == 0) cstoreu_nd(tagp(tg, 1, layer, cu, 0) + g, ep);
  }
}

// C[M][1024] = A[M][1024] @ W^T + bias   (W row-major [1024][1024])
__global__ __launch_bounds__(256)
void gemm_bias(const float* __restrict__ A, const float* __restrict__ W,
               const float* __restrict__ bias, float* __restrict__ C) {
  __shared__ float As[32][65];
  __shared__ float Ws[32][65];
  const int tid = threadIdx.x;
  const int bm = blockIdx.x * 64;
  const int bn = blockIdx.y * 64;
  const int ty = tid >> 4, tx = tid & 15;
  float acc[4][4] = {};
  for (int k0 = 0; k0 < DD; k0 += 32) {
#pragma unroll
    for (int p = 0; p < 2; ++p) {
      const int idx = tid + p * 256;
      const int r = idx >> 3;
      const int cf = idx & 7;
      float4 av = *(const float4*)&A[(size_t)(bm + r) * DD + k0 + cf * 4];
      As[cf*4+0][r] = av.x; As[cf*4+1][r] = av.y; As[cf*4+2][r] = av.z; As[cf*4+3][r] = av.w;
      float4 wv = *(const float4*)&W[(size_t)(bn + r) * DD + k0 + cf * 4];
      Ws[cf*4+0][r] = wv.x; Ws[cf*4+1][r] = wv.y; Ws[cf*4+2][r] = wv.z; Ws[cf*4+3][r] = wv.w;
    }
    __syncthreads();
#pragma unroll
    for (int kk = 0; kk < 32; ++kk) {
      float a[4], w[4];
#pragma unroll
      for (int e = 0; e < 4; ++e) { a[e] = As[kk][ty * 4 + e]; w[e] = Ws[kk][tx * 4 + e]; }
#pragma unroll
      for (int i = 0; i < 4; ++i)
#pragma unroll
        for (int j = 0; j < 4; ++j) acc[i][j] += a[i] * w[j];
    }
    __syncthreads();
  }
#pragma unroll
  for (int i = 0; i < 4; ++i) {
    const int m = bm + ty * 4 + i;
#pragma unroll
    for (int j = 0; j < 4; ++j) {
      const int n = bn + tx * 4 + j;
      C[(size_t)m * DD + n] = acc[i][j] + bias[n];
    }
  }
}

extern "C" void kernel_launch(void* const* d_in, const int* in_sizes, int n_in,
                              void* d_out, int out_size, void* d_ws, size_t ws_size,
                              hipStream_t stream) {
  const float* x  = (const float*)d_in[0];
  const float* Wx = (const float*)d_in[1];
  const float* Wh = (const float*)d_in[2];
  const float* Wr = (const float*)d_in[3];
  const float* U  = (const float*)d_in[4];
  const float* b  = (const float*)d_in[5];
  float* out = (float*)d_out;

  float* pwx = (float*)d_ws;                    // [T][D] fp32 = 32 MB
  float* arena = pwx + (size_t)TT * DD;         // 48*DD floats
  unsigned* tg = (unsigned*)(arena + 48 * DD);  // 2*2*8*64 = 2048 u32

  hipLaunchKernelGGL(init_arena, dim3((48 * DD + 2048 + 255) / 256), dim3(256),
                     0, stream, arena, tg);
  hipLaunchKernelGGL(gemm_bias, dim3(TT / 64, DD / 64), dim3(256), 0, stream,
                     x, Wx, b, pwx);  // layer-1 pwx = x @ Wx1^T + b1

  const float* pwxc = pwx;
  float* arenap = arena;
  unsigned* tgp = tg;
  void* args[] = { (void*)&pwxc, (void*)&Wx, (void*)&Wh, (void*)&Wr,
                   (void*)&U, (void*)&b, (void*)&out, (void*)&arenap, (void*)&tgp };
  hipLaunchCooperativeKernel((const void*)crsd_seq, dim3(NWG), dim3(TPB),
                             args, 0, stream);
}